// Round 7
// baseline (240.001 us; speedup 1.0000x reference)
//
#include <hip/hip_runtime.h>

#define NPTS 8192
#define DIM 64
#define EPSF 1e-7f
#define LN2F 0.69314718055994531f
#define GRID_X 64            // i-blocks of 128 rows
#define GRID_Y 32            // j-blocks of 256 cols
#define TOTAL_BLOCKS (GRID_X * GRID_Y)

typedef unsigned short u16;
typedef __attribute__((ext_vector_type(8))) short bf16x8;   // 8 bf16 (4 VGPRs)
typedef __attribute__((ext_vector_type(8))) unsigned short u16x8;
typedef __attribute__((ext_vector_type(4))) float f32x4;

// ---- kernel 1: split x into bf16 hi/lo; hsq=-sq/2, rcpom=1/(1-sq), m4r=-4/(1-sq).
// Also zeroes S, T and the completion counter (replaces a memset dispatch).
__global__ void prep_kernel(const float* __restrict__ x,
                            u16* __restrict__ hi, u16* __restrict__ lo,
                            float* __restrict__ hsq, float* __restrict__ rcpom,
                            float* __restrict__ m4r,
                            float* __restrict__ S, float* __restrict__ T,
                            int* __restrict__ ctr) {
    int g = blockIdx.x * blockDim.x + threadIdx.x;   // 0 .. NPTS*8-1
    int row = g >> 3, sub = g & 7;
    const float* xp = x + row * DIM + sub * 8;
    float v[8];
    float s = 0.f;
#pragma unroll
    for (int k = 0; k < 8; k++) { v[k] = xp[k]; s = fmaf(v[k], v[k], s); }
    s += __shfl_xor(s, 1);
    s += __shfl_xor(s, 2);
    s += __shfl_xor(s, 4);
    u16x8 h, l;
#pragma unroll
    for (int k = 0; k < 8; k++) {
        unsigned int bits = __float_as_uint(v[k]);
        u16 hb = (u16)(bits >> 16);                       // truncation: hi exact bf16
        float hf = __uint_as_float(((unsigned int)hb) << 16);
        float lf = v[k] - hf;                             // exact in fp32
        u16 lb = (u16)(__float_as_uint(lf) >> 16);
        h[k] = hb; l[k] = lb;
    }
    *(u16x8*)(hi + row * DIM + sub * 8) = h;
    *(u16x8*)(lo + row * DIM + sub * 8) = l;
    if (sub == 0) {
        float r = 1.0f / (1.0f - s);
        hsq[row] = -0.5f * s;
        rcpom[row] = r;
        m4r[row] = -4.0f * r;
    } else if (sub == 1) {
        S[row] = 0.f;
    } else if (sub == 2) {
        T[row] = 0.f;
    }
    if (g == 3) *ctr = 0;
}

// ---- kernel 2: triangular fused MFMA Gram + hyperbolic epilogue -------------
// Block tile 128(i) x 256(j), 4 waves of 32(i) x 256(j). Only tiles with
// bx >= 2*by run (51.5%); tiles fully below the diagonal (bx >= 2by+2) add
// each pair to BOTH row i (regs) and row j (LDS col slab); straddle tiles
// (bx in {2by, 2by+1}) cover the diagonal 256x256 super-tiles in both orders
// directly. B loads double-buffered across t to hide L2 latency.
// Last finishing block runs the finalize inline (done-counter).
__global__ void __launch_bounds__(256, 3) pair_mfma(
        const u16* __restrict__ hi, const u16* __restrict__ lo,
        const float* __restrict__ hsq, const float* __restrict__ rcpom,
        const float* __restrict__ m4r, const int* __restrict__ labels,
        float* __restrict__ Sarr, float* __restrict__ Tarr,
        int* __restrict__ ctr, float* __restrict__ out) {
    __shared__ float slabS[4][256], slabT[4][256];
    __shared__ int hist[16][16];
    __shared__ float cntf[16];
    __shared__ float redf[256];
    __shared__ int isLast;

    int tid = threadIdx.x;
    int bx = blockIdx.x, by = blockIdx.y;
    bool active = (bx >= 2 * by);
    bool full = (bx >= 2 * by + 2);

    if (active) {
        int wave = tid >> 6, lane = tid & 63;
        int quad = lane >> 4, l15 = lane & 15;
        int i0 = bx * 128 + wave * 32;
        int j0 = by * 256;

        bf16x8 a_hi[2][2], a_lo[2][2];
#pragma unroll
        for (int it = 0; it < 2; it++)
#pragma unroll
            for (int ks = 0; ks < 2; ks++) {
                int off = (i0 + it * 16 + l15) * DIM + ks * 32 + quad * 8;
                a_hi[it][ks] = *(const bf16x8*)(hi + off);
                a_lo[it][ks] = *(const bf16x8*)(lo + off);
            }

        float hsqi[8], rcpi[8]; int labi[8];
#pragma unroll
        for (int it = 0; it < 2; it++)
#pragma unroll
            for (int r = 0; r < 4; r++) {
                int row = i0 + it * 16 + quad * 4 + r;
                hsqi[it * 4 + r] = hsq[row];
                rcpi[it * 4 + r] = rcpom[row];
                labi[it * 4 + r] = labels[row];
            }

        if (full) {
            for (int c = lane; c < 256; c += 64) {
                slabS[wave][c] = 0.f;
                slabT[wave][c] = 0.f;
            }
        }

        float Sx[8], Tx[8];
#pragma unroll
        for (int k = 0; k < 8; k++) { Sx[k] = 0.f; Tx[k] = 0.f; }

        // double-buffered B fragments + per-j scalars
        bf16x8 bh[2][2], bl[2][2];
        float hsj[2], mj4[2]; int lbj[2];
        {
            int jg = j0 + l15;
            int off = jg * DIM + quad * 8;
            bh[0][0] = *(const bf16x8*)(hi + off);
            bh[0][1] = *(const bf16x8*)(hi + off + 32);
            bl[0][0] = *(const bf16x8*)(lo + off);
            bl[0][1] = *(const bf16x8*)(lo + off + 32);
            hsj[0] = hsq[jg]; mj4[0] = m4r[jg]; lbj[0] = labels[jg];
        }

#pragma unroll 2
        for (int t = 0; t < 16; t++) {
            int cur = t & 1, nxt = cur ^ 1;
            if (t < 15) {
                int jg = j0 + (t + 1) * 16 + l15;
                int off = jg * DIM + quad * 8;
                bh[nxt][0] = *(const bf16x8*)(hi + off);
                bh[nxt][1] = *(const bf16x8*)(hi + off + 32);
                bl[nxt][0] = *(const bf16x8*)(lo + off);
                bl[nxt][1] = *(const bf16x8*)(lo + off + 32);
                hsj[nxt] = hsq[jg]; mj4[nxt] = m4r[jg]; lbj[nxt] = labels[jg];
            }

            f32x4 ac[2][2];
#pragma unroll
            for (int it = 0; it < 2; it++)
#pragma unroll
                for (int r = 0; r < 4; r++) {
                    ac[it][0][r] = hsqi[it * 4 + r] + hsj[cur];
                    ac[it][1][r] = 0.f;
                }
#pragma unroll
            for (int it = 0; it < 2; it++) {
                ac[it][0] = __builtin_amdgcn_mfma_f32_16x16x32_bf16(a_lo[it][0], bh[cur][0], ac[it][0], 0, 0, 0);
                ac[it][1] = __builtin_amdgcn_mfma_f32_16x16x32_bf16(a_lo[it][1], bh[cur][1], ac[it][1], 0, 0, 0);
                ac[it][0] = __builtin_amdgcn_mfma_f32_16x16x32_bf16(a_hi[it][0], bl[cur][0], ac[it][0], 0, 0, 0);
                ac[it][1] = __builtin_amdgcn_mfma_f32_16x16x32_bf16(a_hi[it][1], bl[cur][1], ac[it][1], 0, 0, 0);
                ac[it][0] = __builtin_amdgcn_mfma_f32_16x16x32_bf16(a_hi[it][0], bh[cur][0], ac[it][0], 0, 0, 0);
                ac[it][1] = __builtin_amdgcn_mfma_f32_16x16x32_bf16(a_hi[it][1], bh[cur][1], ac[it][1], 0, 0, 0);
            }

            float pS = 0.f, pT = 0.f;
#pragma unroll
            for (int it = 0; it < 2; it++)
#pragma unroll
                for (int r = 0; r < 4; r++) {
                    int idx = it * 4 + r;
                    float D = ac[it][0][r] + ac[it][1][r];    // dot - (sqi+sqj)/2
                    float u = fmaxf(D * rcpi[idx] * mj4[cur], EPSF);
                    float srt = __builtin_amdgcn_sqrtf(fmaf(u, u, u + u));
                    float opu = 1.0f + u;
                    float st = opu - srt;                     // exp(-d)
                    float l2 = __builtin_amdgcn_logf(opu + srt); // d/ln2
                    float tv = (lbj[cur] == labi[idx]) ? l2 : 0.0f;
                    Sx[idx] += st; Tx[idx] += tv;
                    if (full) { pS += st; pT += tv; }
                }

            if (full) {
                pS += __shfl_xor(pS, 16); pS += __shfl_xor(pS, 32);
                pT += __shfl_xor(pT, 16); pT += __shfl_xor(pT, 32);
                if (quad == 0) {
                    int c = t * 16 + l15;
                    slabS[wave][c] += pS;
                    slabT[wave][c] += pT;
                }
            }
        }

        // i-side: reduce over the 16 j-columns (l15 lanes within a quad)
#pragma unroll
        for (int r = 0; r < 8; r++) {
#pragma unroll
            for (int m = 1; m < 16; m <<= 1) {
                Sx[r] += __shfl_xor(Sx[r], m);
                Tx[r] += __shfl_xor(Tx[r], m);
            }
        }
        if (l15 == 0) {
#pragma unroll
            for (int it = 0; it < 2; it++)
#pragma unroll
                for (int r = 0; r < 4; r++) {
                    int row = i0 + it * 16 + quad * 4 + r;
                    atomicAdd(&Sarr[row], Sx[it * 4 + r]);
                    atomicAdd(&Tarr[row], Tx[it * 4 + r]);
                }
        }

        // j-side: flush the per-wave column slabs
        if (full) {
            __syncthreads();
            float s = slabS[0][tid] + slabS[1][tid] + slabS[2][tid] + slabS[3][tid];
            float tt = slabT[0][tid] + slabT[1][tid] + slabT[2][tid] + slabT[3][tid];
            atomicAdd(&Sarr[j0 + tid], s);
            atomicAdd(&Tarr[j0 + tid], tt);
        }
    }

    // ---- completion counting; last block finalizes --------------------------
    __threadfence();
    __syncthreads();
    if (tid == 0) {
        int old = atomicAdd(ctr, 1);
        isLast = (old == TOTAL_BLOCKS - 1);
    }
    __syncthreads();
    if (!isLast) return;
    __threadfence();

    // label histogram
    hist[tid >> 4][tid & 15] = 0;
    __syncthreads();
    int rep = tid & 15;
    for (int i = tid; i < NPTS; i += 256)
        atomicAdd(&hist[rep][labels[i]], 1);
    __syncthreads();
    if (tid < 16) {
        int s = 0;
#pragma unroll
        for (int k = 0; k < 16; k++) s += hist[k][tid];
        cntf[tid] = (float)(s - 1);
    }
    __syncthreads();

    float s0 = __builtin_amdgcn_sqrtf(EPSF * (2.0f + EPSF));
    float st0 = 1.0f + EPSF - s0;                         // self exp(-d) term
    float l20 = __builtin_amdgcn_logf(1.0f + EPSF + s0);  // self log2 term
    float acc = 0.f;
    for (int i = tid; i < NPTS; i += 256) {
        float Si = __hip_atomic_load(&Sarr[i], __ATOMIC_RELAXED, __HIP_MEMORY_SCOPE_AGENT);
        float Ti = __hip_atomic_load(&Tarr[i], __ATOMIC_RELAXED, __HIP_MEMORY_SCOPE_AGENT);
        acc += __logf(Si - st0) + (Ti - l20) * LN2F / cntf[labels[i]];
    }
    redf[tid] = acc;
    __syncthreads();
    for (int s = 128; s > 0; s >>= 1) {
        if (tid < s) redf[tid] += redf[tid + s];
        __syncthreads();
    }
    if (tid == 0) out[0] = redf[0];
}

extern "C" void kernel_launch(void* const* d_in, const int* in_sizes, int n_in,
                              void* d_out, int out_size, void* d_ws, size_t ws_size,
                              hipStream_t stream) {
    const float* x = (const float*)d_in[0];
    const int* labels = (const int*)d_in[1];

    u16* hi = (u16*)d_ws;                 // NPTS*DIM u16
    u16* lo = hi + NPTS * DIM;            // NPTS*DIM u16
    float* hsq = (float*)(lo + NPTS * DIM);
    float* rcpom = hsq + NPTS;
    float* m4r = rcpom + NPTS;
    float* S = m4r + NPTS;
    float* T = S + NPTS;
    int* ctr = (int*)(T + NPTS);

    prep_kernel<<<(NPTS * 8) / 256, 256, 0, stream>>>(x, hi, lo, hsq, rcpom, m4r, S, T, ctr);

    dim3 grid(GRID_X, GRID_Y);
    pair_mfma<<<grid, 256, 0, stream>>>(hi, lo, hsq, rcpom, m4r, labels, S, T, ctr, (float*)d_out);
}

// Round 8
// 133.822 us; speedup vs baseline: 1.7934x; 1.7934x over previous
//
#include <hip/hip_runtime.h>

#define NPTS 8192
#define DIM 64
#define EPSF 1e-7f
#define LN2F 0.69314718055994531f

typedef unsigned short u16;
typedef __attribute__((ext_vector_type(8))) short bf16x8;   // 8 bf16 (4 VGPRs)
typedef __attribute__((ext_vector_type(8))) unsigned short u16x8;
typedef __attribute__((ext_vector_type(4))) float f32x4;

// ---- kernel 1: split x into bf16 hi/lo; hsq=-sq/2, rcpom=1/(1-sq), m4r=-4/(1-sq)
// Also zeroes S, T, out (replaces the memset dispatch).
__global__ void prep_kernel(const float* __restrict__ x,
                            u16* __restrict__ hi, u16* __restrict__ lo,
                            float* __restrict__ hsq, float* __restrict__ rcpom,
                            float* __restrict__ m4r,
                            float* __restrict__ S, float* __restrict__ T,
                            float* __restrict__ out) {
    int g = blockIdx.x * blockDim.x + threadIdx.x;   // 0 .. NPTS*8-1
    int row = g >> 3, sub = g & 7;
    const float* xp = x + row * DIM + sub * 8;
    float v[8];
    float s = 0.f;
#pragma unroll
    for (int k = 0; k < 8; k++) { v[k] = xp[k]; s = fmaf(v[k], v[k], s); }
    s += __shfl_xor(s, 1);
    s += __shfl_xor(s, 2);
    s += __shfl_xor(s, 4);
    u16x8 h, l;
#pragma unroll
    for (int k = 0; k < 8; k++) {
        unsigned int bits = __float_as_uint(v[k]);
        u16 hb = (u16)(bits >> 16);                       // truncation: hi exact bf16
        float hf = __uint_as_float(((unsigned int)hb) << 16);
        float lf = v[k] - hf;                             // exact in fp32
        u16 lb = (u16)(__float_as_uint(lf) >> 16);
        h[k] = hb; l[k] = lb;
    }
    *(u16x8*)(hi + row * DIM + sub * 8) = h;
    *(u16x8*)(lo + row * DIM + sub * 8) = l;
    if (sub == 0) {
        float r = 1.0f / (1.0f - s);
        hsq[row] = -0.5f * s;
        rcpom[row] = r;
        m4r[row] = -4.0f * r;
    } else if (sub == 1) {
        S[row] = 0.f;
    } else if (sub == 2) {
        T[row] = 0.f;
    }
    if (g == 3) out[0] = 0.f;
}

// ---- kernel 2: fused MFMA Gram tile + hyperbolic epilogue -------------------
// Block tile 128(i) x 256(j); 4 waves, wave tile 32(i) x 256(j).  (Round-5
// structure: 79.6us, VGPR 56, MfmaUtil 12.4, VALUBusy 39.)  unroll 4 lets the
// scheduler hoist several iterations' B loads (latency hiding); no fences, no
// LDS, no done-counter — R7 showed per-block device fences collapse the grid.
__global__ void __launch_bounds__(256, 3) pair_mfma(
        const u16* __restrict__ hi, const u16* __restrict__ lo,
        const float* __restrict__ hsq, const float* __restrict__ rcpom,
        const float* __restrict__ m4r, const int* __restrict__ labels,
        float* __restrict__ Sarr, float* __restrict__ Tarr) {
    int tid = threadIdx.x;
    int wave = tid >> 6, lane = tid & 63;
    int quad = lane >> 4, l15 = lane & 15;
    int i0 = blockIdx.x * 128 + wave * 32;
    int j0 = blockIdx.y * 256;

    bf16x8 a_hi[2][2], a_lo[2][2];
#pragma unroll
    for (int it = 0; it < 2; it++)
#pragma unroll
        for (int ks = 0; ks < 2; ks++) {
            int off = (i0 + it * 16 + l15) * DIM + ks * 32 + quad * 8;
            a_hi[it][ks] = *(const bf16x8*)(hi + off);
            a_lo[it][ks] = *(const bf16x8*)(lo + off);
        }

    float hsqi[8], rcpi[8]; int labi[8];
#pragma unroll
    for (int it = 0; it < 2; it++)
#pragma unroll
        for (int r = 0; r < 4; r++) {
            int row = i0 + it * 16 + quad * 4 + r;
            hsqi[it * 4 + r] = hsq[row];
            rcpi[it * 4 + r] = rcpom[row];
            labi[it * 4 + r] = labels[row];
        }

    float Sx[8], Tx[8];
#pragma unroll
    for (int k = 0; k < 8; k++) { Sx[k] = 0.f; Tx[k] = 0.f; }

#pragma unroll 4
    for (int t = 0; t < 16; t++) {
        int jg = j0 + t * 16 + l15;
        bf16x8 b_hi[2], b_lo[2];
#pragma unroll
        for (int ks = 0; ks < 2; ks++) {
            int off = jg * DIM + ks * 32 + quad * 8;
            b_hi[ks] = *(const bf16x8*)(hi + off);
            b_lo[ks] = *(const bf16x8*)(lo + off);
        }
        float hsqj = hsq[jg];
        float mj = m4r[jg];
        int labj = labels[jg];

#pragma unroll
        for (int it = 0; it < 2; it++) {
            f32x4 acc0, acc1;
#pragma unroll
            for (int r = 0; r < 4; r++) { acc0[r] = hsqi[it * 4 + r] + hsqj; acc1[r] = 0.f; }
            acc0 = __builtin_amdgcn_mfma_f32_16x16x32_bf16(a_lo[it][0], b_hi[0], acc0, 0, 0, 0);
            acc1 = __builtin_amdgcn_mfma_f32_16x16x32_bf16(a_lo[it][1], b_hi[1], acc1, 0, 0, 0);
            acc0 = __builtin_amdgcn_mfma_f32_16x16x32_bf16(a_hi[it][0], b_lo[0], acc0, 0, 0, 0);
            acc1 = __builtin_amdgcn_mfma_f32_16x16x32_bf16(a_hi[it][1], b_lo[1], acc1, 0, 0, 0);
            acc0 = __builtin_amdgcn_mfma_f32_16x16x32_bf16(a_hi[it][0], b_hi[0], acc0, 0, 0, 0);
            acc1 = __builtin_amdgcn_mfma_f32_16x16x32_bf16(a_hi[it][1], b_hi[1], acc1, 0, 0, 0);

#pragma unroll
            for (int r = 0; r < 4; r++) {
                int idx = it * 4 + r;
                float D = acc0[r] + acc1[r];                  // dot - (sqi+sqj)/2
                float u = fmaxf(D * rcpi[idx] * mj, EPSF);
                float srt = __builtin_amdgcn_sqrtf(fmaf(u, u, u + u));
                float opu = 1.0f + u;
                Sx[idx] += opu - srt;                         // exp(-d)
                float l2 = __builtin_amdgcn_logf(opu + srt);  // d / ln2
                Tx[idx] += (labj == labi[idx]) ? l2 : 0.0f;
            }
        }
    }

    // reduce across the 16 j-columns (lanes within a quad share rows)
#pragma unroll
    for (int r = 0; r < 8; r++) {
#pragma unroll
        for (int m = 1; m < 16; m <<= 1) {
            Sx[r] += __shfl_xor(Sx[r], m);
            Tx[r] += __shfl_xor(Tx[r], m);
        }
    }
    if (l15 == 0) {
#pragma unroll
        for (int it = 0; it < 2; it++)
#pragma unroll
            for (int r = 0; r < 4; r++) {
                int row = i0 + it * 16 + quad * 4 + r;
                atomicAdd(&Sarr[row], Sx[it * 4 + r]);
                atomicAdd(&Tarr[row], Tx[it * 4 + r]);
            }
    }
}

// ---- kernel 3: finalize, 32 parallel blocks ---------------------------------
// Each block builds the 16-bin label histogram itself (8K L2-hot reads), then
// handles its 256 rows: loss_i = ln(S_i - st0) + ln2*(T_i - l20)/(cnt-1).
__global__ void __launch_bounds__(256) finalize_kernel(
        const float* __restrict__ S, const float* __restrict__ T,
        const int* __restrict__ labels, float* __restrict__ out) {
    __shared__ int hist[16][16];
    __shared__ float cntf[16];
    __shared__ float red[256];
    int tid = threadIdx.x;
    hist[tid >> 4][tid & 15] = 0;
    __syncthreads();
    int rep = tid & 15;
    for (int i = tid; i < NPTS; i += 256)
        atomicAdd(&hist[rep][labels[i]], 1);
    __syncthreads();
    if (tid < 16) {
        int s = 0;
#pragma unroll
        for (int k = 0; k < 16; k++) s += hist[k][tid];
        cntf[tid] = (float)(s - 1);
    }
    __syncthreads();

    float s0 = __builtin_amdgcn_sqrtf(EPSF * (2.0f + EPSF));
    float st0 = 1.0f + EPSF - s0;                         // self exp(-d) term
    float l20 = __builtin_amdgcn_logf(1.0f + EPSF + s0);  // self log2 term
    int i = blockIdx.x * 256 + tid;
    float loss = __logf(S[i] - st0) + (T[i] - l20) * LN2F / cntf[labels[i]];
    red[tid] = loss;
    __syncthreads();
    for (int s = 128; s > 0; s >>= 1) {
        if (tid < s) red[tid] += red[tid + s];
        __syncthreads();
    }
    if (tid == 0) atomicAdd(out, red[0]);
}

extern "C" void kernel_launch(void* const* d_in, const int* in_sizes, int n_in,
                              void* d_out, int out_size, void* d_ws, size_t ws_size,
                              hipStream_t stream) {
    const float* x = (const float*)d_in[0];
    const int* labels = (const int*)d_in[1];

    u16* hi = (u16*)d_ws;                 // NPTS*DIM u16
    u16* lo = hi + NPTS * DIM;            // NPTS*DIM u16
    float* hsq = (float*)(lo + NPTS * DIM);
    float* rcpom = hsq + NPTS;
    float* m4r = rcpom + NPTS;
    float* S = m4r + NPTS;
    float* T = S + NPTS;

    prep_kernel<<<(NPTS * 8) / 256, 256, 0, stream>>>(x, hi, lo, hsq, rcpom, m4r, S, T, (float*)d_out);

    dim3 grid(NPTS / 128, NPTS / 256);
    pair_mfma<<<grid, 256, 0, stream>>>(hi, lo, hsq, rcpom, m4r, labels, S, T);

    finalize_kernel<<<NPTS / 256, 256, 0, stream>>>(S, T, labels, (float*)d_out);
}

// Round 9
// 120.241 us; speedup vs baseline: 1.9960x; 1.1129x over previous
//
#include <hip/hip_runtime.h>

#define NPTS 8192
#define DIM 64
#define EPSF 1e-7f
#define LN2F 0.69314718055994531f
#define NBLK 1056   // sum_{by=0}^{31} (64 - 2*by)

typedef unsigned short u16;
typedef __attribute__((ext_vector_type(8))) short bf16x8;   // 8 bf16 (4 VGPRs)
typedef __attribute__((ext_vector_type(8))) unsigned short u16x8;
typedef __attribute__((ext_vector_type(4))) float f32x4;

// ---- kernel 1: split x into bf16 hi/lo; hsq=-sq/2, rcpom=1/(1-sq), m4r=-4/(1-sq)
// Also zeroes S, T, out (replaces the memset dispatch).
__global__ void prep_kernel(const float* __restrict__ x,
                            u16* __restrict__ hi, u16* __restrict__ lo,
                            float* __restrict__ hsq, float* __restrict__ rcpom,
                            float* __restrict__ m4r,
                            float* __restrict__ S, float* __restrict__ T,
                            float* __restrict__ out) {
    int g = blockIdx.x * blockDim.x + threadIdx.x;   // 0 .. NPTS*8-1
    int row = g >> 3, sub = g & 7;
    const float* xp = x + row * DIM + sub * 8;
    float v[8];
    float s = 0.f;
#pragma unroll
    for (int k = 0; k < 8; k++) { v[k] = xp[k]; s = fmaf(v[k], v[k], s); }
    s += __shfl_xor(s, 1);
    s += __shfl_xor(s, 2);
    s += __shfl_xor(s, 4);
    u16x8 h, l;
#pragma unroll
    for (int k = 0; k < 8; k++) {
        unsigned int bits = __float_as_uint(v[k]);
        u16 hb = (u16)(bits >> 16);                       // truncation: hi exact bf16
        float hf = __uint_as_float(((unsigned int)hb) << 16);
        float lf = v[k] - hf;                             // exact in fp32
        u16 lb = (u16)(__float_as_uint(lf) >> 16);
        h[k] = hb; l[k] = lb;
    }
    *(u16x8*)(hi + row * DIM + sub * 8) = h;
    *(u16x8*)(lo + row * DIM + sub * 8) = l;
    if (sub == 0) {
        float r = 1.0f / (1.0f - s);
        hsq[row] = -0.5f * s;
        rcpom[row] = r;
        m4r[row] = -4.0f * r;
    } else if (sub == 1) {
        S[row] = 0.f;
    } else if (sub == 2) {
        T[row] = 0.f;
    }
    if (g == 3) out[0] = 0.f;
}

// C(b) = number of active tiles with by < b
__device__ __forceinline__ int cumtiles(int b) { return 65 * b - b * b; }

// ---- kernel 2: triangular fused MFMA Gram + hyperbolic epilogue -------------
// 1056 active tiles only: block tile 128(i) x 256(j), active iff bx >= 2*by.
// Straddle tiles (bx-2by in {0,1}) do i-side only; full tiles (bx >= 2by+2)
// accumulate each pair to BOTH row i (regs) and row j (per-wave LDS slab,
// flushed once at block end). No fences, no done-counter (R7 lesson).
// Inner structure identical to the proven R5/R8 kernel (79.6us).
__global__ void __launch_bounds__(256, 3) pair_mfma(
        const u16* __restrict__ hi, const u16* __restrict__ lo,
        const float* __restrict__ hsq, const float* __restrict__ rcpom,
        const float* __restrict__ m4r, const int* __restrict__ labels,
        float* __restrict__ Sarr, float* __restrict__ Tarr) {
    __shared__ float slabS[4][256], slabT[4][256];

    int tid = threadIdx.x;
    // invert linear block id -> (by, bx) in the triangular tile set
    int bid = blockIdx.x;
    int by = (int)((65.0f - __builtin_amdgcn_sqrtf(4225.0f - 4.0f * (float)bid)) * 0.5f);
    while (cumtiles(by + 1) <= bid) by++;
    while (cumtiles(by) > bid) by--;
    int off = bid - cumtiles(by);
    int bx = 2 * by + off;
    bool full = (off >= 2);

    int wave = tid >> 6, lane = tid & 63;
    int quad = lane >> 4, l15 = lane & 15;
    int i0 = bx * 128 + wave * 32;
    int j0 = by * 256;

    bf16x8 a_hi[2][2], a_lo[2][2];
#pragma unroll
    for (int it = 0; it < 2; it++)
#pragma unroll
        for (int ks = 0; ks < 2; ks++) {
            int aoff = (i0 + it * 16 + l15) * DIM + ks * 32 + quad * 8;
            a_hi[it][ks] = *(const bf16x8*)(hi + aoff);
            a_lo[it][ks] = *(const bf16x8*)(lo + aoff);
        }

    float hsqi[8], rcpi[8]; int labi[8];
#pragma unroll
    for (int it = 0; it < 2; it++)
#pragma unroll
        for (int r = 0; r < 4; r++) {
            int row = i0 + it * 16 + quad * 4 + r;
            hsqi[it * 4 + r] = hsq[row];
            rcpi[it * 4 + r] = rcpom[row];
            labi[it * 4 + r] = labels[row];
        }

    if (full) {
        for (int c = tid; c < 256; c += 256) { /* each thread owns one col */ }
        slabS[wave][lane] = 0.f;       slabT[wave][lane] = 0.f;
        slabS[wave][lane + 64] = 0.f;  slabT[wave][lane + 64] = 0.f;
        slabS[wave][lane + 128] = 0.f; slabT[wave][lane + 128] = 0.f;
        slabS[wave][lane + 192] = 0.f; slabT[wave][lane + 192] = 0.f;
    }

    float Sx[8], Tx[8];
#pragma unroll
    for (int k = 0; k < 8; k++) { Sx[k] = 0.f; Tx[k] = 0.f; }

#pragma unroll 2
    for (int t = 0; t < 16; t++) {
        int jg = j0 + t * 16 + l15;
        bf16x8 b_hi[2], b_lo[2];
#pragma unroll
        for (int ks = 0; ks < 2; ks++) {
            int boff = jg * DIM + ks * 32 + quad * 8;
            b_hi[ks] = *(const bf16x8*)(hi + boff);
            b_lo[ks] = *(const bf16x8*)(lo + boff);
        }
        float hsqj = hsq[jg];
        float mj = m4r[jg];
        int labj = labels[jg];

        float pS = 0.f, pT = 0.f;
#pragma unroll
        for (int it = 0; it < 2; it++) {
            f32x4 acc0, acc1;
#pragma unroll
            for (int r = 0; r < 4; r++) { acc0[r] = hsqi[it * 4 + r] + hsqj; acc1[r] = 0.f; }
            acc0 = __builtin_amdgcn_mfma_f32_16x16x32_bf16(a_lo[it][0], b_hi[0], acc0, 0, 0, 0);
            acc1 = __builtin_amdgcn_mfma_f32_16x16x32_bf16(a_lo[it][1], b_hi[1], acc1, 0, 0, 0);
            acc0 = __builtin_amdgcn_mfma_f32_16x16x32_bf16(a_hi[it][0], b_lo[0], acc0, 0, 0, 0);
            acc1 = __builtin_amdgcn_mfma_f32_16x16x32_bf16(a_hi[it][1], b_lo[1], acc1, 0, 0, 0);
            acc0 = __builtin_amdgcn_mfma_f32_16x16x32_bf16(a_hi[it][0], b_hi[0], acc0, 0, 0, 0);
            acc1 = __builtin_amdgcn_mfma_f32_16x16x32_bf16(a_hi[it][1], b_hi[1], acc1, 0, 0, 0);

#pragma unroll
            for (int r = 0; r < 4; r++) {
                int idx = it * 4 + r;
                float D = acc0[r] + acc1[r];                  // dot - (sqi+sqj)/2
                float u = fmaxf(D * rcpi[idx] * mj, EPSF);
                float srt = __builtin_amdgcn_sqrtf(fmaf(u, u, u + u));
                float opu = 1.0f + u;
                float st = opu - srt;                         // exp(-d)
                float l2 = __builtin_amdgcn_logf(opu + srt);  // d / ln2
                float tv = (labj == labi[idx]) ? l2 : 0.0f;
                Sx[idx] += st;
                Tx[idx] += tv;
                pS += st; pT += tv;
            }
        }

        if (full) {
            // sum the 4 quads -> full 32-row partial for column jg
            pS += __shfl_xor(pS, 16); pS += __shfl_xor(pS, 32);
            pT += __shfl_xor(pT, 16); pT += __shfl_xor(pT, 32);
            if (quad == 0) {
                int c = t * 16 + l15;
                slabS[wave][c] += pS;
                slabT[wave][c] += pT;
            }
        }
    }

    // i-side: reduce across the 16 j-columns (lanes within a quad share rows)
#pragma unroll
    for (int r = 0; r < 8; r++) {
#pragma unroll
        for (int m = 1; m < 16; m <<= 1) {
            Sx[r] += __shfl_xor(Sx[r], m);
            Tx[r] += __shfl_xor(Tx[r], m);
        }
    }
    if (l15 == 0) {
#pragma unroll
        for (int it = 0; it < 2; it++)
#pragma unroll
            for (int r = 0; r < 4; r++) {
                int row = i0 + it * 16 + quad * 4 + r;
                atomicAdd(&Sarr[row], Sx[it * 4 + r]);
                atomicAdd(&Tarr[row], Tx[it * 4 + r]);
            }
    }

    // j-side: flush per-wave slabs (full tiles only; branch is block-uniform)
    if (full) {
        __syncthreads();
        float s = slabS[0][tid] + slabS[1][tid] + slabS[2][tid] + slabS[3][tid];
        float tt = slabT[0][tid] + slabT[1][tid] + slabT[2][tid] + slabT[3][tid];
        atomicAdd(&Sarr[j0 + tid], s);
        atomicAdd(&Tarr[j0 + tid], tt);
    }
}

// ---- kernel 3: finalize, 32 parallel blocks ---------------------------------
__global__ void __launch_bounds__(256) finalize_kernel(
        const float* __restrict__ S, const float* __restrict__ T,
        const int* __restrict__ labels, float* __restrict__ out) {
    __shared__ int hist[16][16];
    __shared__ float cntf[16];
    __shared__ float red[256];
    int tid = threadIdx.x;
    hist[tid >> 4][tid & 15] = 0;
    __syncthreads();
    int rep = tid & 15;
    for (int i = tid; i < NPTS; i += 256)
        atomicAdd(&hist[rep][labels[i]], 1);
    __syncthreads();
    if (tid < 16) {
        int s = 0;
#pragma unroll
        for (int k = 0; k < 16; k++) s += hist[k][tid];
        cntf[tid] = (float)(s - 1);
    }
    __syncthreads();

    float s0 = __builtin_amdgcn_sqrtf(EPSF * (2.0f + EPSF));
    float st0 = 1.0f + EPSF - s0;                         // self exp(-d) term
    float l20 = __builtin_amdgcn_logf(1.0f + EPSF + s0);  // self log2 term
    int i = blockIdx.x * 256 + tid;
    float loss = __logf(S[i] - st0) + (T[i] - l20) * LN2F / cntf[labels[i]];
    red[tid] = loss;
    __syncthreads();
    for (int s = 128; s > 0; s >>= 1) {
        if (tid < s) red[tid] += red[tid + s];
        __syncthreads();
    }
    if (tid == 0) atomicAdd(out, red[0]);
}

extern "C" void kernel_launch(void* const* d_in, const int* in_sizes, int n_in,
                              void* d_out, int out_size, void* d_ws, size_t ws_size,
                              hipStream_t stream) {
    const float* x = (const float*)d_in[0];
    const int* labels = (const int*)d_in[1];

    u16* hi = (u16*)d_ws;                 // NPTS*DIM u16
    u16* lo = hi + NPTS * DIM;            // NPTS*DIM u16
    float* hsq = (float*)(lo + NPTS * DIM);
    float* rcpom = hsq + NPTS;
    float* m4r = rcpom + NPTS;
    float* S = m4r + NPTS;
    float* T = S + NPTS;

    prep_kernel<<<(NPTS * 8) / 256, 256, 0, stream>>>(x, hi, lo, hsq, rcpom, m4r, S, T, (float*)d_out);

    pair_mfma<<<NBLK, 256, 0, stream>>>(hi, lo, hsq, rcpom, m4r, labels, S, T);

    finalize_kernel<<<NPTS / 256, 256, 0, stream>>>(S, T, labels, (float*)d_out);
}